// Round 15
// baseline (467.889 us; speedup 1.0000x reference)
//
#include <hip/hip_runtime.h>
#include <hip/hip_fp16.h>

// Problem constants (fixed by the reference)
#define NG    4096        // graphs
#define NPG   198         // nodes per graph
#define EPG   1584        // edges per graph
#define ETOT  (NG * EPG)  // total edges
#define SHW   12          // feature row stride in words (24 halves, 48 B)

#define BC2(u) __builtin_bit_cast(__half2, (u))

typedef _Float16 f16x4 __attribute__((ext_vector_type(4)));
typedef float    f32x4 __attribute__((ext_vector_type(4)));
typedef float    f32x2 __attribute__((ext_vector_type(2)));

// Workspace layout (f16 units):
#define H_F16S    (NG * 396)
#define WTB_SZ    114688
#define WTB1_OFF  83200
#define WTB2_OFF  106496
#define WTB3_OFF  113664
#define CPK_PAIRS 562

// ---------------------------------------------------------------------------
// Merged weight pack (single launch): MLP WTB hi/lo + conv float2 pairs.
// ---------------------------------------------------------------------------
__global__ __launch_bounds__(256) void wpack_kernel(
    const float* __restrict__ w0, const float* __restrict__ w1,
    const float* __restrict__ w2, const float* __restrict__ w3,
    const float* wr0, const float* wq0, const float* wr1, const float* wq1,
    const float* wr2, const float* wq2, const float* wr3, const float* wq3,
    const float* wr4, const float* wq4,
    _Float16* __restrict__ wtb, f32x2* __restrict__ cpk)
{
    const int idx = blockIdx.x * 256 + threadIdx.x;
    if (idx < 2 * WTB_SZ) {
        const int half = idx >= WTB_SZ;
        const int rel0 = idx - half * WTB_SZ;
        const float* w; int K, N, NPAD, rel;
        if (rel0 < 83200)       { w = w0; K = 396; N = 200; NPAD = 208; rel = rel0; }
        else if (rel0 < 106496) { w = w1; K = 200; N = 100; NPAD = 112; rel = rel0 - 83200; }
        else if (rel0 < 113664) { w = w2; K = 100; N = 50;  NPAD = 64;  rel = rel0 - 106496; }
        else                    { w = w3; K = 50;  N = 10;  NPAD = 16;  rel = rel0 - 113664; }
        const int span = NPAD * 16;
        const int kc = rel / span;
        const int r  = rel - kc * span;
        const int n  = r >> 4, ki = r & 15;
        const int k  = kc * 16 + ki;
        const float v = (n < N && k < K) ? w[n * K + k] : 0.f;
        const _Float16 hi = (_Float16)v;
        wtb[idx] = half ? (_Float16)(v - (float)hi) : hi;
        return;
    }
    const int cidx = idx - 2 * WTB_SZ;
    if (cidx >= CPK_PAIRS) return;
    const float *wrel, *wroot; int COUT, CIN, MSP, base;
    if (cidx < 40)       { wrel=wr0; wroot=wq0; COUT=20; CIN=2;  MSP=1;  base=0;   }
    else if (cidx < 340) { wrel=wr1; wroot=wq1; COUT=15; CIN=20; MSP=10; base=40;  }
    else if (cidx < 500) { wrel=wr2; wroot=wq2; COUT=10; CIN=15; MSP=8;  base=340; }
    else if (cidx < 550) { wrel=wr3; wroot=wq3; COUT=5;  CIN=10; MSP=5;  base=500; }
    else                 { wrel=wr4; wroot=wq4; COUT=2;  CIN=5;  MSP=3;  base=550; }
    const int r    = cidx - base;
    const int half = r >= COUT * MSP;
    const int q    = r - half * COUT * MSP;
    const int o    = q / MSP, p = q - o * MSP;
    const float* w = half ? wroot : wrel;
    const int c0 = 2 * p, c1 = 2 * p + 1;
    f32x2 v;
    v.x = (c0 < CIN) ? w[o * CIN + c0] : 0.f;
    v.y = (c1 < CIN) ? w[o * CIN + c1] : 0.f;
    cpk[cidx] = v;
}

// ---------------------------------------------------------------------------
// Pair-split conv layer: node k owned by adjacent lanes 2k (half 0) and 2k+1
// (half 1). Each gathers half the dst-segment (f32 accum, v_fma_mix), the
// halves merge via in-wave __shfl_xor(1) (add commutes -> bit-identical on
// both lanes, deterministic), then each computes half the dense outputs
// (v_pk_fma_f32) and stores its word range (rows fully written, zero-padded).
// ---------------------------------------------------------------------------
template <int CIN, int COUT, int SIN, int SOUT>
__device__ __forceinline__ void conv_layer_pair(
    const unsigned* __restrict__ h_in,   // rows stride SIN words
    unsigned* __restrict__ h_out,        // rows stride SOUT words
    const unsigned* __restrict__ s_edge, // (f16w<<16)|src, sorted by dst
    const unsigned short* __restrict__ row_start,
    const unsigned short* __restrict__ perm,
    const f32x2* __restrict__ wrelp,     // [COUT][MS] packed pairs
    const f32x2* __restrict__ wrootp,    // [COUT][MS]
    const float* __restrict__ brel, int tid)
{
    if (tid >= 2 * NPG) return;
    const int node = (int)perm[tid >> 1];
    const int half = tid & 1;
    constexpr int MS   = (CIN + 1) / 2;
    constexpr int SPL  = (COUT / 2 + 1) & ~1;     // even channel split point
    constexpr int NH1  = COUT - SPL;
    constexpr int MAXO = (SPL > NH1) ? SPL : NH1;

    float aggf[MS * 2];
#pragma unroll
    for (int c = 0; c < MS * 2; ++c) aggf[c] = 0.f;

    {
        const unsigned jb0 = row_start[node], je0 = row_start[node + 1];
        const unsigned mid = jb0 + ((je0 - jb0 + 1) >> 1);
        const unsigned jb = half ? mid : jb0;
        const unsigned je = half ? je0 : mid;
        for (unsigned j = jb; j < je; ++j) {
            const unsigned e  = s_edge[j];
            const float    wf = __half2float(__ushort_as_half((unsigned short)(e >> 16)));
            const unsigned* row = h_in + (e & 0xFFFFu) * SIN;
            unsigned wv[MS];
            if constexpr (SIN == 1) {
                wv[0] = row[0];
            } else {
                const uint4 q0 = *(const uint4*)row;
                wv[0] = q0.x;
                if constexpr (MS > 1) wv[1] = q0.y;
                if constexpr (MS > 2) wv[2] = q0.z;
                if constexpr (MS > 3) wv[3] = q0.w;
                if constexpr (MS > 4) {
                    const uint4 q1 = *(const uint4*)(row + 4);
                    wv[4] = q1.x;
                    if constexpr (MS > 5) wv[5] = q1.y;
                    if constexpr (MS > 6) wv[6] = q1.z;
                    if constexpr (MS > 7) wv[7] = q1.w;
                }
                if constexpr (MS > 8) {
                    const uint4 q2 = *(const uint4*)(row + 8);
                    wv[8] = q2.x;
                    if constexpr (MS > 9) wv[9] = q2.y;
                }
            }
#pragma unroll
            for (int p = 0; p < MS; ++p) {
                const __half2 h2 = BC2(wv[p]);
                aggf[2*p]     = fmaf(wf, __low2float(h2),  aggf[2*p]);
                aggf[2*p + 1] = fmaf(wf, __high2float(h2), aggf[2*p + 1]);
            }
        }
    }

    // merge partner's partial: same-wave lanes (2k,2k+1); a+b bit-commutative
#pragma unroll
    for (int c = 0; c < MS * 2; ++c)
        aggf[c] += __shfl_xor(aggf[c], 1);

    // own row (both lanes read the same address -> broadcast)
    float hv[MS * 2];
    {
        const unsigned* me = h_in + node * SIN;
        unsigned mw[MS];
        if constexpr (SIN == 1) {
            mw[0] = me[0];
        } else {
            const uint4 q0 = *(const uint4*)me;
            mw[0] = q0.x;
            if constexpr (MS > 1) mw[1] = q0.y;
            if constexpr (MS > 2) mw[2] = q0.z;
            if constexpr (MS > 3) mw[3] = q0.w;
            if constexpr (MS > 4) {
                const uint4 q1 = *(const uint4*)(me + 4);
                mw[4] = q1.x;
                if constexpr (MS > 5) mw[5] = q1.y;
                if constexpr (MS > 6) mw[6] = q1.z;
                if constexpr (MS > 7) mw[7] = q1.w;
            }
            if constexpr (MS > 8) {
                const uint4 q2 = *(const uint4*)(me + 8);
                mw[8] = q2.x;
                if constexpr (MS > 9) mw[9] = q2.y;
            }
        }
#pragma unroll
        for (int p = 0; p < MS; ++p) {
            const __half2 h2 = BC2(mw[p]);
            hv[2*p]     = __low2float(h2);
            hv[2*p + 1] = __high2float(h2);
        }
    }

    // dense: half 0 -> outputs [0,SPL), half 1 -> [SPL,COUT). Static outv idx.
    float outv[MAXO];
    const int nout  = half ? NH1 : SPL;
    const int obase = half ? SPL : 0;
#pragma unroll
    for (int i = 0; i < MAXO; ++i) {
        if (i < nout) {
            const int o = obase + i;
            f32x2 acc; acc.x = brel[o]; acc.y = 0.f;
#pragma unroll
            for (int p = 0; p < MS; ++p) {
                f32x2 av;  av.x  = aggf[2*p]; av.y  = aggf[2*p+1];
                acc = __builtin_elementwise_fma(av,  wrelp[o * MS + p], acc);
                f32x2 hv2; hv2.x = hv[2*p];   hv2.y = hv[2*p+1];
                acc = __builtin_elementwise_fma(hv2, wrootp[o * MS + p], acc);
            }
            outv[i] = fmaxf(acc.x + acc.y, 0.f);
        }
    }

    // store: half 0 words [0, SPL/2), half 1 words [SPL/2, SOUT) (zero-pad)
    unsigned* orow = h_out + node * SOUT;
    if (half == 0) {
#pragma unroll
        for (int w = 0; w < SPL / 2; ++w)
            orow[w] = __builtin_bit_cast(unsigned,
                __floats2half2_rn(outv[2*w], outv[2*w+1]));
    } else {
#pragma unroll
        for (int w = SPL / 2; w < SOUT; ++w) {
            const int i = 2 * w - SPL;
            const float lo = (i     < NH1) ? outv[i]     : 0.f;
            const float hi = (i + 1 < NH1) ? outv[i + 1] : 0.f;
            orow[w] = __builtin_bit_cast(unsigned, __floats2half2_rn(lo, hi));
        }
    }
}

__global__ __launch_bounds__(512) void conv_kernel(
    const float* __restrict__ x,
    const int*   __restrict__ eidx,
    const float* __restrict__ ew,
    const f32x2* __restrict__ cpk,
    const float* __restrict__ br0, const float* __restrict__ br1,
    const float* __restrict__ br2, const float* __restrict__ br3,
    const float* __restrict__ br4,
    _Float16* __restrict__ H)            // row-major [NG][396] f16
{
    __shared__ __align__(16) unsigned s_edge[EPG];            // 6336 B
    __shared__ unsigned       cnt[256];                       // counts -> cursor
    __shared__ unsigned short row_start[NPG + 2];
    __shared__ unsigned       wsum[4];
    __shared__ unsigned       dhist[64];
    __shared__ unsigned       dcur[64];
    __shared__ unsigned short perm[NPG + 2];
    __shared__ __align__(16) unsigned bufA[NPG * SHW];        // 9504 B
    __shared__ __align__(16) unsigned bufB[NPG * SHW];        // 9504 B

    const int g = blockIdx.x, tid = threadIdx.x;
    const int ebase = g * EPG, nbase = g * NPG;
    const int lane = tid & 63, wid = tid >> 6;

    // --- load edges: 396 quads, one per thread ------------------------------
    const int4*   s4 = (const int4*)(eidx + ebase);
    const int4*   d4 = (const int4*)(eidx + ETOT + ebase);
    const float4* w4 = (const float4*)(ew + ebase);
    const bool havq = tid < (EPG / 4);   // 396
    int4 sa = {0,0,0,0}, da = {0,0,0,0}; float4 wa = {0,0,0,0};
    if (havq) { sa = s4[tid]; da = d4[tid]; wa = w4[tid]; }

    if (tid < 256) cnt[tid] = 0u;
    __syncthreads();
    if (havq) {
        atomicAdd(&cnt[da.x - nbase], 1u); atomicAdd(&cnt[da.y - nbase], 1u);
        atomicAdd(&cnt[da.z - nbase], 1u); atomicAdd(&cnt[da.w - nbase], 1u);
    }
    __syncthreads();

    // --- exclusive scan over 256 bins (waves 0..3) --------------------------
    unsigned v = 0;
    if (tid < 256) {
        v = cnt[tid];
        unsigned inc = v;
#pragma unroll
        for (int s = 1; s < 64; s <<= 1) {
            const unsigned t = (unsigned)__shfl_up((int)inc, s);
            if (lane >= s) inc += t;
        }
        if (lane == 63) wsum[wid] = inc;
        __syncthreads();
        unsigned pre = 0;
        for (int w = 0; w < wid; ++w) pre += wsum[w];
        const unsigned excl = pre + inc - v;
        if (tid <= NPG) row_start[tid] = (unsigned short)excl;   // [198]==EPG
        cnt[tid] = excl;                  // cnt becomes the placement cursor
    } else {
        __syncthreads();
    }
    __syncthreads();

    // --- place edges sorted by dst: pack (f16w<<16)|src ---------------------
    if (havq) {
        auto place = [&](int s, int d, float w) {
            const int dl = d - nbase;
            const unsigned slot = atomicAdd(&cnt[dl], 1u);
            const __half hw = __float2half_rn(w);
            s_edge[slot] = ((unsigned)__half_as_ushort(hw) << 16)
                         | (unsigned)(s - nbase);
        };
        place(sa.x, da.x, wa.x); place(sa.y, da.y, wa.y);
        place(sa.z, da.z, wa.z); place(sa.w, da.w, wa.w);
    }

    // pack x (198 x 2 fp32) into half2 words of bufA (stride 1)
    if (tid < NPG) {
        const float2 xv = ((const float2*)x)[nbase + tid];
        bufA[tid] = __builtin_bit_cast(unsigned, __floats2half2_rn(xv.x, xv.y));
    }

    // --- degree-sorted permutation (counting sort over 64 degree bins) ------
    if (tid < 64) dhist[tid] = 0u;
    __syncthreads();
    unsigned mydeg = 0u;
    if (tid < NPG) {
        mydeg = v; if (mydeg > 63u) mydeg = 63u;
        atomicAdd(&dhist[mydeg], 1u);
    }
    __syncthreads();
    if (tid < 64) {
        const unsigned dv = dhist[tid];
        unsigned sc = dv;
#pragma unroll
        for (int s = 1; s < 64; s <<= 1) {
            const unsigned t = (unsigned)__shfl_up((int)sc, s);
            if (lane >= s) sc += t;
        }
        dcur[tid] = sc - dv;
    }
    __syncthreads();
    if (tid < NPG) {
        const unsigned pos = atomicAdd(&dcur[mydeg], 1u);
        perm[pos] = (unsigned short)tid;
    }
    __syncthreads();

    // --- 5 layers, one barrier each (cpk bases: 0,40,340,500,550 pairs) -----
    conv_layer_pair<2,  20, 1,   SHW>(bufA, bufB, s_edge, row_start, perm,
                                      cpk + 0,   cpk + 20,        br0, tid);
    __syncthreads();
    conv_layer_pair<20, 15, SHW, SHW>(bufB, bufA, s_edge, row_start, perm,
                                      cpk + 40,  cpk + 40 + 150,  br1, tid);
    __syncthreads();
    conv_layer_pair<15, 10, SHW, SHW>(bufA, bufB, s_edge, row_start, perm,
                                      cpk + 340, cpk + 340 + 80,  br2, tid);
    __syncthreads();
    conv_layer_pair<10, 5,  SHW, SHW>(bufB, bufA, s_edge, row_start, perm,
                                      cpk + 500, cpk + 500 + 25,  br3, tid);
    __syncthreads();
    conv_layer_pair<5,  2,  SHW, 1  >(bufA, bufB, s_edge, row_start, perm,
                                      cpk + 550, cpk + 550 + 6,   br4, tid);
    __syncthreads();

    // --- row-major f16 store: H[g][396] -------------------------------------
    if (tid < NPG)
        ((unsigned*)H)[g * NPG + tid] = bufB[tid];
}

// ---------------------------------------------------------------------------
// MLP as fused MFMA GEMM chain with hi/lo weight split (validated r11/r14).
// 8 graphs per block (512 blocks = 2 blocks/CU, 16 waves/CU).
// ---------------------------------------------------------------------------
__device__ __forceinline__ void zero_words(void* p, int nwords, int tid)
{
    unsigned* u = (unsigned*)p;
    for (int i = tid; i < nwords; i += 512) u[i] = 0u;
}

template<int KC, int NTT, int NOUT, int SIN, int SOUT>
__device__ __forceinline__ void mfma_layer(
    const _Float16* __restrict__ inb,
    _Float16* __restrict__ outb,
    const _Float16* __restrict__ wthi,
    const _Float16* __restrict__ wtlo,
    const float* __restrict__ bias, int tid)
{
    constexpr int NPAD = NTT * 16;
    const int lane = tid & 63, wid = tid >> 6;
    const int lrow = lane & 15, lgrp = lane >> 4;
    const int nt0 = wid;
    if (nt0 >= NTT) return;
    const bool has2 = (nt0 + 8) < NTT;
    const _Float16* aptr = inb + lrow * SIN + lgrp * 4;

    f32x4 acc0 = {0.f, 0.f, 0.f, 0.f};
    f32x4 acc1 = {0.f, 0.f, 0.f, 0.f};
    const int n0 = nt0 * 16 + lrow;
    const int n1 = (nt0 + 8) * 16 + lrow;
    const int boff0 = n0 * 16 + lgrp * 4;
    const int boff1 = n1 * 16 + lgrp * 4;
#pragma unroll 4
    for (int kc = 0; kc < KC; ++kc) {
        const f16x4 a = *(const f16x4*)(aptr + kc * 16);
        const size_t kb = (size_t)kc * (NPAD * 16);
        acc0 = __builtin_amdgcn_mfma_f32_16x16x16f16(
            a, *(const f16x4*)(wthi + kb + boff0), acc0, 0, 0, 0);
        acc0 = __builtin_amdgcn_mfma_f32_16x16x16f16(
            a, *(const f16x4*)(wtlo + kb + boff0), acc0, 0, 0, 0);
        if (has2) {
            acc1 = __builtin_amdgcn_mfma_f32_16x16x16f16(
                a, *(const f16x4*)(wthi + kb + boff1), acc1, 0, 0, 0);
            acc1 = __builtin_amdgcn_mfma_f32_16x16x16f16(
                a, *(const f16x4*)(wtlo + kb + boff1), acc1, 0, 0, 0);
        }
    }
    if (n0 < NOUT) {
        const float bv = bias[n0];
#pragma unroll
        for (int j = 0; j < 4; ++j)
            outb[(lgrp * 4 + j) * SOUT + n0] = (_Float16)fmaxf(acc0[j] + bv, 0.f);
    }
    if (has2 && n1 < NOUT) {
        const float bv = bias[n1];
#pragma unroll
        for (int j = 0; j < 4; ++j)
            outb[(lgrp * 4 + j) * SOUT + n1] = (_Float16)fmaxf(acc1[j] + bv, 0.f);
    }
}

__global__ __launch_bounds__(512) void mlp_mfma_kernel(
    const _Float16* __restrict__ H,
    const _Float16* __restrict__ wtb,
    const float* __restrict__ lb0, const float* __restrict__ lb1,
    const float* __restrict__ lb2, const float* __restrict__ lb3,
    const float* __restrict__ lw4, const float* __restrict__ lb4,
    float* __restrict__ out)
{
    __shared__ __align__(16) _Float16 bufH[16 * 400];
    __shared__ __align__(16) _Float16 bufX[16 * 224];
    __shared__ __align__(16) _Float16 bufY[16 * 128];

    const int tid   = threadIdx.x;
    const int gbase = blockIdx.x * 8;          // 8 graphs per block
    const _Float16* lo = wtb + WTB_SZ;

    {
        const unsigned* Hw = (const unsigned*)H + (size_t)gbase * 198;
        unsigned* bH = (unsigned*)bufH;
        for (int t = tid; t < 16 * 200; t += 512) {
            const int gg = t / 200, w = t - gg * 200;
            bH[gg * 200 + w] = (gg < 8 && w < 198) ? Hw[gg * 198 + w] : 0u;
        }
        zero_words(bufX, 16 * 224 / 2, tid);
        zero_words(bufY, 16 * 128 / 2, tid);
    }
    __syncthreads();

    mfma_layer<25, 13, 200, 400, 224>(bufH, bufX, wtb, lo, lb0, tid);
    __syncthreads();

    zero_words(bufH, 512, tid);
    mfma_layer<13, 7, 100, 224, 128>(bufX, bufY, wtb + WTB1_OFF, lo + WTB1_OFF, lb1, tid);
    __syncthreads();

    zero_words(bufX, 128, tid);
    mfma_layer<7, 4, 50, 128, 64>(bufY, bufH, wtb + WTB2_OFF, lo + WTB2_OFF, lb2, tid);
    __syncthreads();

    mfma_layer<4, 1, 10, 64, 16>(bufH, bufX, wtb + WTB3_OFF, lo + WTB3_OFF, lb3, tid);
    __syncthreads();

    if (tid < 8) {
        float l0 = lb4[0], l1 = lb4[1];
#pragma unroll
        for (int k = 0; k < 10; ++k) {
            const float hv = (float)bufX[tid * 16 + k];
            l0 = fmaf(hv, lw4[k],      l0);
            l1 = fmaf(hv, lw4[10 + k], l1);
        }
        const float m  = fmaxf(l0, l1);
        const float e0 = __expf(l0 - m), e1 = __expf(l1 - m);
        const float inv = 1.f / (e0 + e1);
        float2 p; p.x = e0 * inv; p.y = e1 * inv;
        ((float2*)out)[gbase + tid] = p;
    }
}

extern "C" void kernel_launch(void* const* d_in, const int* in_sizes, int n_in,
                              void* d_out, int out_size, void* d_ws, size_t ws_size,
                              hipStream_t stream)
{
    const float* x    = (const float*)d_in[0];
    const int*   eidx = (const int*)  d_in[1];
    const float* ew   = (const float*)d_in[2];

    const float* wr[5]; const float* br[5]; const float* wq[5];
    for (int i = 0; i < 5; ++i) {
        wr[i] = (const float*)d_in[3 + 3 * i];
        br[i] = (const float*)d_in[4 + 3 * i];
        wq[i] = (const float*)d_in[5 + 3 * i];
    }
    const float* lw[5]; const float* lb[5];
    for (int i = 0; i < 5; ++i) {
        lw[i] = (const float*)d_in[18 + 2 * i];
        lb[i] = (const float*)d_in[19 + 2 * i];
    }

    _Float16* wsH = (_Float16*)d_ws;                  // H: [NG][396] f16
    _Float16* wtb = wsH + (size_t)H_F16S;             // MLP weights hi+lo
    f32x2*    cpk = (f32x2*)(wtb + (size_t)(2 * WTB_SZ));  // conv packed pairs

    const int total_pack = 2 * WTB_SZ + CPK_PAIRS;
    wpack_kernel<<<(total_pack + 255) / 256, 256, 0, stream>>>(
        lw[0], lw[1], lw[2], lw[3],
        wr[0], wq[0], wr[1], wq[1], wr[2], wq[2], wr[3], wq[3], wr[4], wq[4],
        wtb, cpk);

    conv_kernel<<<NG, 512, 0, stream>>>(
        x, eidx, ew, cpk,
        br[0], br[1], br[2], br[3], br[4],
        wsH);

    mlp_mfma_kernel<<<NG / 8, 512, 0, stream>>>(
        wsH, wtb,
        lb[0], lb[1], lb[2], lb[3],
        lw[4], lb[4],
        (float*)d_out);
}

// Round 16
// 117.453 us; speedup vs baseline: 3.9836x; 3.9836x over previous
//
#include <hip/hip_runtime.h>
#include <hip/hip_fp16.h>

// Problem constants (fixed by the reference)
#define NG    4096        // graphs
#define NPG   198         // nodes per graph
#define EPG   1584        // edges per graph
#define ETOT  (NG * EPG)  // total edges
#define SHW   12          // feature row stride in words (24 halves, 48 B)

#define BC2(u) __builtin_bit_cast(__half2, (u))

typedef _Float16 f16x4 __attribute__((ext_vector_type(4)));
typedef float    f32x4 __attribute__((ext_vector_type(4)));
typedef float    f32x2 __attribute__((ext_vector_type(2)));

// Workspace layout (f16 units):
#define H_F16S    (NG * 396)
#define WTB_SZ    114688
#define WTB1_OFF  83200
#define WTB2_OFF  106496
#define WTB3_OFF  113664
#define CPK_PAIRS 562

// ---------------------------------------------------------------------------
// Merged weight pack (single launch): MLP WTB hi/lo + conv float2 pairs.
// ---------------------------------------------------------------------------
__global__ __launch_bounds__(256) void wpack_kernel(
    const float* __restrict__ w0, const float* __restrict__ w1,
    const float* __restrict__ w2, const float* __restrict__ w3,
    const float* wr0, const float* wq0, const float* wr1, const float* wq1,
    const float* wr2, const float* wq2, const float* wr3, const float* wq3,
    const float* wr4, const float* wq4,
    _Float16* __restrict__ wtb, f32x2* __restrict__ cpk)
{
    const int idx = blockIdx.x * 256 + threadIdx.x;
    if (idx < 2 * WTB_SZ) {
        const int half = idx >= WTB_SZ;
        const int rel0 = idx - half * WTB_SZ;
        const float* w; int K, N, NPAD, rel;
        if (rel0 < 83200)       { w = w0; K = 396; N = 200; NPAD = 208; rel = rel0; }
        else if (rel0 < 106496) { w = w1; K = 200; N = 100; NPAD = 112; rel = rel0 - 83200; }
        else if (rel0 < 113664) { w = w2; K = 100; N = 50;  NPAD = 64;  rel = rel0 - 106496; }
        else                    { w = w3; K = 50;  N = 10;  NPAD = 16;  rel = rel0 - 113664; }
        const int span = NPAD * 16;
        const int kc = rel / span;
        const int r  = rel - kc * span;
        const int n  = r >> 4, ki = r & 15;
        const int k  = kc * 16 + ki;
        const float v = (n < N && k < K) ? w[n * K + k] : 0.f;
        const _Float16 hi = (_Float16)v;
        wtb[idx] = half ? (_Float16)(v - (float)hi) : hi;
        return;
    }
    const int cidx = idx - 2 * WTB_SZ;
    if (cidx >= CPK_PAIRS) return;
    const float *wrel, *wroot; int COUT, CIN, MSP, base;
    if (cidx < 40)       { wrel=wr0; wroot=wq0; COUT=20; CIN=2;  MSP=1;  base=0;   }
    else if (cidx < 340) { wrel=wr1; wroot=wq1; COUT=15; CIN=20; MSP=10; base=40;  }
    else if (cidx < 500) { wrel=wr2; wroot=wq2; COUT=10; CIN=15; MSP=8;  base=340; }
    else if (cidx < 550) { wrel=wr3; wroot=wq3; COUT=5;  CIN=10; MSP=5;  base=500; }
    else                 { wrel=wr4; wroot=wq4; COUT=2;  CIN=5;  MSP=3;  base=550; }
    const int r    = cidx - base;
    const int half = r >= COUT * MSP;
    const int q    = r - half * COUT * MSP;
    const int o    = q / MSP, p = q - o * MSP;
    const float* w = half ? wroot : wrel;
    const int c0 = 2 * p, c1 = 2 * p + 1;
    f32x2 v;
    v.x = (c0 < CIN) ? w[o * CIN + c0] : 0.f;
    v.y = (c1 < CIN) ? w[o * CIN + c1] : 0.f;
    cpk[cidx] = v;
}

// ---------------------------------------------------------------------------
// Conv layer (round-13, measured 96 us): node-per-thread gather with f32
// accumulation (v_fma_mix, deterministic), dense via packed f32 pairs
// (v_pk_fma_f32). Feature rows stride 12 words, uint4 reads.
// ---------------------------------------------------------------------------
template <int CIN, int COUT, int SIN, int SOUT>
__device__ __forceinline__ void conv_layer_h(
    const unsigned* __restrict__ h_in,   // rows stride SIN (half2 words)
    unsigned* __restrict__ h_out,        // rows stride SOUT
    const unsigned* __restrict__ s_edge, // (f16w<<16)|src, sorted by dst
    const unsigned* __restrict__ row_start,
    const unsigned short* __restrict__ perm,
    const f32x2* __restrict__ wrelp,     // [COUT][MS] packed pairs
    const f32x2* __restrict__ wrootp,    // [COUT][MS]
    const float* __restrict__ brel, int tid)
{
    if (tid >= NPG) return;
    const int node = (int)perm[tid];
    constexpr int MS = (CIN + 1) / 2;

    float aggf[MS * 2];
#pragma unroll
    for (int c = 0; c < MS * 2; ++c) aggf[c] = 0.f;

    const unsigned jb = row_start[node], je = row_start[node + 1];
    for (unsigned j = jb; j < je; ++j) {
        const unsigned e  = s_edge[j];
        const float    wf = __half2float(__ushort_as_half((unsigned short)(e >> 16)));
        const unsigned* row = h_in + (e & 0xFFFFu) * SIN;
        unsigned wv[MS];
        if constexpr (SIN == 1) {
            wv[0] = row[0];
        } else {
            const uint4 q0 = *(const uint4*)row;
            wv[0] = q0.x;
            if constexpr (MS > 1) wv[1] = q0.y;
            if constexpr (MS > 2) wv[2] = q0.z;
            if constexpr (MS > 3) wv[3] = q0.w;
            if constexpr (MS > 4) {
                const uint4 q1 = *(const uint4*)(row + 4);
                wv[4] = q1.x;
                if constexpr (MS > 5) wv[5] = q1.y;
                if constexpr (MS > 6) wv[6] = q1.z;
                if constexpr (MS > 7) wv[7] = q1.w;
            }
            if constexpr (MS > 8) {
                const uint4 q2 = *(const uint4*)(row + 8);
                wv[8] = q2.x;
                if constexpr (MS > 9) wv[9] = q2.y;
            }
        }
#pragma unroll
        for (int p = 0; p < MS; ++p) {
            const __half2 h2 = BC2(wv[p]);
            aggf[2*p]     = fmaf(wf, __low2float(h2),  aggf[2*p]);
            aggf[2*p + 1] = fmaf(wf, __high2float(h2), aggf[2*p + 1]);
        }
    }

    float hv[MS * 2];
    {
        const unsigned* me = h_in + node * SIN;
#pragma unroll
        for (int p = 0; p < MS; ++p) {
            const __half2 h2 = BC2(me[p]);
            hv[2*p]     = __low2float(h2);
            hv[2*p + 1] = __high2float(h2);
        }
    }

    // dense via packed f32 pairs -> v_pk_fma_f32
    float outv[COUT];
#pragma unroll
    for (int o = 0; o < COUT; ++o) {
        f32x2 acc; acc.x = brel[o]; acc.y = 0.f;
#pragma unroll
        for (int p = 0; p < MS; ++p) {
            f32x2 av; av.x = aggf[2*p]; av.y = aggf[2*p+1];
            acc = __builtin_elementwise_fma(av, wrelp[o * MS + p], acc);
            f32x2 hv2; hv2.x = hv[2*p]; hv2.y = hv[2*p+1];
            acc = __builtin_elementwise_fma(hv2, wrootp[o * MS + p], acc);
        }
        outv[o] = fmaxf(acc.x + acc.y, 0.f);
    }

    if constexpr (SOUT == 1) {
        h_out[node] = __builtin_bit_cast(unsigned,
            __floats2half2_rn(outv[0], COUT > 1 ? outv[1] : 0.f));
    } else {
        unsigned ow[SOUT];
#pragma unroll
        for (int p = 0; p < SOUT; ++p) {
            const float lo = (2 * p     < COUT) ? outv[2 * p]     : 0.f;
            const float hi = (2 * p + 1 < COUT) ? outv[2 * p + 1] : 0.f;
            ow[p] = __builtin_bit_cast(unsigned, __floats2half2_rn(lo, hi));
        }
        unsigned* orow = h_out + node * SOUT;
#pragma unroll
        for (int qn = 0; qn < SOUT / 4; ++qn)
            *(uint4*)(orow + 4 * qn) =
                make_uint4(ow[4*qn], ow[4*qn+1], ow[4*qn+2], ow[4*qn+3]);
    }
}

__global__ __launch_bounds__(256) void conv_kernel(
    const float* __restrict__ x,
    const int*   __restrict__ eidx,
    const float* __restrict__ ew,
    const f32x2* __restrict__ cpk,
    const float* __restrict__ br0, const float* __restrict__ br1,
    const float* __restrict__ br2, const float* __restrict__ br3,
    const float* __restrict__ br4,
    _Float16* __restrict__ H)            // row-major [NG][396] f16
{
    __shared__ __align__(16) unsigned s_edge[EPG];            // 6336 B
    __shared__ unsigned       cnt[256];
    __shared__ unsigned       cursor[256];
    __shared__ unsigned       row_start[NPG + 1];
    __shared__ unsigned       wsum[4];
    __shared__ unsigned       dhist[64];
    __shared__ unsigned       dcur[64];
    __shared__ unsigned short perm[NPG + 2];
    __shared__ __align__(16) unsigned bufA[NPG * SHW];        // 9504 B
    __shared__ __align__(16) unsigned bufB[NPG * SHW];        // 9504 B

    const int g = blockIdx.x, tid = threadIdx.x;
    const int ebase = g * EPG, nbase = g * NPG;
    const int lane = tid & 63, wid = tid >> 6;

    // --- zero feature buffers (pad halves must be 0) ------------------------
    for (int i = tid; i < NPG * SHW; i += 256) { bufA[i] = 0u; bufB[i] = 0u; }

    // --- load all edges once into registers (396 quads over 256 threads) ----
    const int4*   s4 = (const int4*)(eidx + ebase);
    const int4*   d4 = (const int4*)(eidx + ETOT + ebase);
    const float4* w4 = (const float4*)(ew + ebase);
    const int4   sa = s4[tid];
    const int4   da = d4[tid];
    const float4 wa = w4[tid];
    const bool hasb = tid < (EPG / 4 - 256);   // threads 0..139
    int4 sb = {0,0,0,0}, db = {0,0,0,0}; float4 wb = {0,0,0,0};
    if (hasb) { sb = s4[tid + 256]; db = d4[tid + 256]; wb = w4[tid + 256]; }

    cnt[tid] = 0u;
    __syncthreads();
    atomicAdd(&cnt[da.x - nbase], 1u); atomicAdd(&cnt[da.y - nbase], 1u);
    atomicAdd(&cnt[da.z - nbase], 1u); atomicAdd(&cnt[da.w - nbase], 1u);
    if (hasb) {
        atomicAdd(&cnt[db.x - nbase], 1u); atomicAdd(&cnt[db.y - nbase], 1u);
        atomicAdd(&cnt[db.z - nbase], 1u); atomicAdd(&cnt[db.w - nbase], 1u);
    }
    __syncthreads();

    // --- exclusive scan (wave shfl + cross-wave combine) --------------------
    const unsigned v = cnt[tid];
    unsigned inc = v;
#pragma unroll
    for (int s = 1; s < 64; s <<= 1) {
        const unsigned t = (unsigned)__shfl_up((int)inc, s);
        if (lane >= s) inc += t;
    }
    if (lane == 63) wsum[wid] = inc;
    __syncthreads();
    unsigned pre = 0;
    for (int w = 0; w < wid; ++w) pre += wsum[w];
    const unsigned excl = pre + inc - v;
    if (tid <= NPG) row_start[tid] = excl;   // row_start[198] == EPG
    if (tid < NPG)  cursor[tid]    = excl;
    __syncthreads();

    // --- place edges sorted by dst: pack (f16w<<16)|src ---------------------
    {
        auto place = [&](int s, int d, float w) {
            const int dl = d - nbase;
            const unsigned slot = atomicAdd(&cursor[dl], 1u);
            const __half hw = __float2half_rn(w);
            s_edge[slot] = ((unsigned)__half_as_ushort(hw) << 16)
                         | (unsigned)(s - nbase);
        };
        place(sa.x, da.x, wa.x); place(sa.y, da.y, wa.y);
        place(sa.z, da.z, wa.z); place(sa.w, da.w, wa.w);
        if (hasb) {
            place(sb.x, db.x, wb.x); place(sb.y, db.y, wb.y);
            place(sb.z, db.z, wb.z); place(sb.w, db.w, wb.w);
        }
    }

    // pack x (198 x 2 fp32) into half2 words of bufA (stride 1)
    if (tid < NPG) {
        const float2 xv = ((const float2*)x)[nbase + tid];
        bufA[tid] = __builtin_bit_cast(unsigned, __floats2half2_rn(xv.x, xv.y));
    }

    // --- degree-sorted permutation (counting sort over 64 degree bins) ------
    if (tid < 64) dhist[tid] = 0u;
    __syncthreads();
    unsigned mydeg = 0u;
    if (tid < NPG) {
        mydeg = v; if (mydeg > 63u) mydeg = 63u;
        atomicAdd(&dhist[mydeg], 1u);
    }
    __syncthreads();
    if (tid < 64) {
        const unsigned dv = dhist[tid];
        unsigned sc = dv;
#pragma unroll
        for (int s = 1; s < 64; s <<= 1) {
            const unsigned t = (unsigned)__shfl_up((int)sc, s);
            if (lane >= s) sc += t;
        }
        dcur[tid] = sc - dv;
    }
    __syncthreads();
    if (tid < NPG) {
        const unsigned pos = atomicAdd(&dcur[mydeg], 1u);
        perm[pos] = (unsigned short)tid;
    }
    __syncthreads();

    // --- 5 layers, one barrier each (cpk bases: 0,40,340,500,550 pairs) -----
    conv_layer_h<2,  20, 1,   SHW>(bufA, bufB, s_edge, row_start, perm,
                                   cpk + 0,   cpk + 20,        br0, tid);
    __syncthreads();
    conv_layer_h<20, 15, SHW, SHW>(bufB, bufA, s_edge, row_start, perm,
                                   cpk + 40,  cpk + 40 + 150,  br1, tid);
    __syncthreads();
    conv_layer_h<15, 10, SHW, SHW>(bufA, bufB, s_edge, row_start, perm,
                                   cpk + 340, cpk + 340 + 80,  br2, tid);
    __syncthreads();
    conv_layer_h<10, 5,  SHW, SHW>(bufB, bufA, s_edge, row_start, perm,
                                   cpk + 500, cpk + 500 + 25,  br3, tid);
    __syncthreads();
    conv_layer_h<5,  2,  SHW, 1  >(bufA, bufB, s_edge, row_start, perm,
                                   cpk + 550, cpk + 550 + 6,   br4, tid);
    __syncthreads();

    // --- row-major f16 store: H[g][396] (word = half2 of ch 0,1 per node) ---
    if (tid < NPG)
        ((unsigned*)H)[g * NPG + tid] = bufB[tid];
}

// ---------------------------------------------------------------------------
// MLP as fused MFMA GEMM chain with hi/lo weight split (validated r11/r14).
// 8 graphs per block (512 blocks = 2 blocks/CU, 16 waves/CU).
// ---------------------------------------------------------------------------
__device__ __forceinline__ void zero_words(void* p, int nwords, int tid)
{
    unsigned* u = (unsigned*)p;
    for (int i = tid; i < nwords; i += 512) u[i] = 0u;
}

template<int KC, int NTT, int NOUT, int SIN, int SOUT>
__device__ __forceinline__ void mfma_layer(
    const _Float16* __restrict__ inb,
    _Float16* __restrict__ outb,
    const _Float16* __restrict__ wthi,
    const _Float16* __restrict__ wtlo,
    const float* __restrict__ bias, int tid)
{
    constexpr int NPAD = NTT * 16;
    const int lane = tid & 63, wid = tid >> 6;
    const int lrow = lane & 15, lgrp = lane >> 4;
    const int nt0 = wid;
    if (nt0 >= NTT) return;
    const bool has2 = (nt0 + 8) < NTT;
    const _Float16* aptr = inb + lrow * SIN + lgrp * 4;

    f32x4 acc0 = {0.f, 0.f, 0.f, 0.f};
    f32x4 acc1 = {0.f, 0.f, 0.f, 0.f};
    const int n0 = nt0 * 16 + lrow;
    const int n1 = (nt0 + 8) * 16 + lrow;
    const int boff0 = n0 * 16 + lgrp * 4;
    const int boff1 = n1 * 16 + lgrp * 4;
#pragma unroll 4
    for (int kc = 0; kc < KC; ++kc) {
        const f16x4 a = *(const f16x4*)(aptr + kc * 16);
        const size_t kb = (size_t)kc * (NPAD * 16);
        acc0 = __builtin_amdgcn_mfma_f32_16x16x16f16(
            a, *(const f16x4*)(wthi + kb + boff0), acc0, 0, 0, 0);
        acc0 = __builtin_amdgcn_mfma_f32_16x16x16f16(
            a, *(const f16x4*)(wtlo + kb + boff0), acc0, 0, 0, 0);
        if (has2) {
            acc1 = __builtin_amdgcn_mfma_f32_16x16x16f16(
                a, *(const f16x4*)(wthi + kb + boff1), acc1, 0, 0, 0);
            acc1 = __builtin_amdgcn_mfma_f32_16x16x16f16(
                a, *(const f16x4*)(wtlo + kb + boff1), acc1, 0, 0, 0);
        }
    }
    if (n0 < NOUT) {
        const float bv = bias[n0];
#pragma unroll
        for (int j = 0; j < 4; ++j)
            outb[(lgrp * 4 + j) * SOUT + n0] = (_Float16)fmaxf(acc0[j] + bv, 0.f);
    }
    if (has2 && n1 < NOUT) {
        const float bv = bias[n1];
#pragma unroll
        for (int j = 0; j < 4; ++j)
            outb[(lgrp * 4 + j) * SOUT + n1] = (_Float16)fmaxf(acc1[j] + bv, 0.f);
    }
}

__global__ __launch_bounds__(512) void mlp_mfma_kernel(
    const _Float16* __restrict__ H,
    const _Float16* __restrict__ wtb,
    const float* __restrict__ lb0, const float* __restrict__ lb1,
    const float* __restrict__ lb2, const float* __restrict__ lb3,
    const float* __restrict__ lw4, const float* __restrict__ lb4,
    float* __restrict__ out)
{
    __shared__ __align__(16) _Float16 bufH[16 * 400];
    __shared__ __align__(16) _Float16 bufX[16 * 224];
    __shared__ __align__(16) _Float16 bufY[16 * 128];

    const int tid   = threadIdx.x;
    const int gbase = blockIdx.x * 8;          // 8 graphs per block
    const _Float16* lo = wtb + WTB_SZ;

    {
        const unsigned* Hw = (const unsigned*)H + (size_t)gbase * 198;
        unsigned* bH = (unsigned*)bufH;
        for (int t = tid; t < 16 * 200; t += 512) {
            const int gg = t / 200, w = t - gg * 200;
            bH[gg * 200 + w] = (gg < 8 && w < 198) ? Hw[gg * 198 + w] : 0u;
        }
        zero_words(bufX, 16 * 224 / 2, tid);
        zero_words(bufY, 16 * 128 / 2, tid);
    }
    __syncthreads();

    mfma_layer<25, 13, 200, 400, 224>(bufH, bufX, wtb, lo, lb0, tid);
    __syncthreads();

    zero_words(bufH, 512, tid);
    mfma_layer<13, 7, 100, 224, 128>(bufX, bufY, wtb + WTB1_OFF, lo + WTB1_OFF, lb1, tid);
    __syncthreads();

    zero_words(bufX, 128, tid);
    mfma_layer<7, 4, 50, 128, 64>(bufY, bufH, wtb + WTB2_OFF, lo + WTB2_OFF, lb2, tid);
    __syncthreads();

    mfma_layer<4, 1, 10, 64, 16>(bufH, bufX, wtb + WTB3_OFF, lo + WTB3_OFF, lb3, tid);
    __syncthreads();

    if (tid < 8) {
        float l0 = lb4[0], l1 = lb4[1];
#pragma unroll
        for (int k = 0; k < 10; ++k) {
            const float hv = (float)bufX[tid * 16 + k];
            l0 = fmaf(hv, lw4[k],      l0);
            l1 = fmaf(hv, lw4[10 + k], l1);
        }
        const float m  = fmaxf(l0, l1);
        const float e0 = __expf(l0 - m), e1 = __expf(l1 - m);
        const float inv = 1.f / (e0 + e1);
        float2 p; p.x = e0 * inv; p.y = e1 * inv;
        ((float2*)out)[gbase + tid] = p;
    }
}

extern "C" void kernel_launch(void* const* d_in, const int* in_sizes, int n_in,
                              void* d_out, int out_size, void* d_ws, size_t ws_size,
                              hipStream_t stream)
{
    const float* x    = (const float*)d_in[0];
    const int*   eidx = (const int*)  d_in[1];
    const float* ew   = (const float*)d_in[2];

    const float* wr[5]; const float* br[5]; const float* wq[5];
    for (int i = 0; i < 5; ++i) {
        wr[i] = (const float*)d_in[3 + 3 * i];
        br[i] = (const float*)d_in[4 + 3 * i];
        wq[i] = (const float*)d_in[5 + 3 * i];
    }
    const float* lw[5]; const float* lb[5];
    for (int i = 0; i < 5; ++i) {
        lw[i] = (const float*)d_in[18 + 2 * i];
        lb[i] = (const float*)d_in[19 + 2 * i];
    }

    _Float16* wsH = (_Float16*)d_ws;                  // H: [NG][396] f16
    _Float16* wtb = wsH + (size_t)H_F16S;             // MLP weights hi+lo
    f32x2*    cpk = (f32x2*)(wtb + (size_t)(2 * WTB_SZ));  // conv packed pairs

    const int total_pack = 2 * WTB_SZ + CPK_PAIRS;
    wpack_kernel<<<(total_pack + 255) / 256, 256, 0, stream>>>(
        lw[0], lw[1], lw[2], lw[3],
        wr[0], wq[0], wr[1], wq[1], wr[2], wq[2], wr[3], wq[3], wr[4], wq[4],
        wtb, cpk);

    conv_kernel<<<NG, 256, 0, stream>>>(
        x, eidx, ew, cpk,
        br[0], br[1], br[2], br[3], br[4],
        wsH);

    mlp_mfma_kernel<<<NG / 8, 512, 0, stream>>>(
        wsH, wtb,
        lb[0], lb[1], lb[2], lb[3],
        lw[4], lb[4],
        (float*)d_out);
}

// Round 17
// 114.851 us; speedup vs baseline: 4.0739x; 1.0227x over previous
//
#include <hip/hip_runtime.h>
#include <hip/hip_fp16.h>

// Problem constants (fixed by the reference)
#define NG    4096        // graphs
#define NPG   198         // nodes per graph
#define EPG   1584        // edges per graph
#define ETOT  (NG * EPG)  // total edges
#define SHW   12          // feature row stride in words (24 halves, 48 B)

#define BC2(u)  __builtin_bit_cast(__half2, (u))
#define BCH2(u) __builtin_bit_cast(f16x2, (u))

typedef _Float16 f16x2 __attribute__((ext_vector_type(2)));
typedef _Float16 f16x4 __attribute__((ext_vector_type(4)));
typedef float    f32x4 __attribute__((ext_vector_type(4)));

// Workspace layout (f16 units):
//   H   [NG][396] f16
//   WTB hi (114,688) + lo (114,688)   (MLP B-fragment weights)
//   CHK conv weights as half2 channel-pairs (562 dwords)
#define H_F16S    (NG * 396)
#define WTB_SZ    114688
#define WTB1_OFF  83200
#define WTB2_OFF  106496
#define WTB3_OFF  113664
#define CHK_PAIRS 562

// ---------------------------------------------------------------------------
// Merged weight pack (single launch): MLP WTB hi/lo + conv half2 pairs.
// ---------------------------------------------------------------------------
__global__ __launch_bounds__(256) void wpack_kernel(
    const float* __restrict__ w0, const float* __restrict__ w1,
    const float* __restrict__ w2, const float* __restrict__ w3,
    const float* wr0, const float* wq0, const float* wr1, const float* wq1,
    const float* wr2, const float* wq2, const float* wr3, const float* wq3,
    const float* wr4, const float* wq4,
    _Float16* __restrict__ wtb, unsigned* __restrict__ chk)
{
    const int idx = blockIdx.x * 256 + threadIdx.x;
    if (idx < 2 * WTB_SZ) {
        const int half = idx >= WTB_SZ;
        const int rel0 = idx - half * WTB_SZ;
        const float* w; int K, N, NPAD, rel;
        if (rel0 < 83200)       { w = w0; K = 396; N = 200; NPAD = 208; rel = rel0; }
        else if (rel0 < 106496) { w = w1; K = 200; N = 100; NPAD = 112; rel = rel0 - 83200; }
        else if (rel0 < 113664) { w = w2; K = 100; N = 50;  NPAD = 64;  rel = rel0 - 106496; }
        else                    { w = w3; K = 50;  N = 10;  NPAD = 16;  rel = rel0 - 113664; }
        const int span = NPAD * 16;
        const int kc = rel / span;
        const int r  = rel - kc * span;
        const int n  = r >> 4, ki = r & 15;
        const int k  = kc * 16 + ki;
        const float v = (n < N && k < K) ? w[n * K + k] : 0.f;
        const _Float16 hi = (_Float16)v;
        wtb[idx] = half ? (_Float16)(v - (float)hi) : hi;
        return;
    }
    const int cidx = idx - 2 * WTB_SZ;
    if (cidx >= CHK_PAIRS) return;
    const float *wrel, *wroot; int COUT, CIN, MSP, base;
    if (cidx < 40)       { wrel=wr0; wroot=wq0; COUT=20; CIN=2;  MSP=1;  base=0;   }
    else if (cidx < 340) { wrel=wr1; wroot=wq1; COUT=15; CIN=20; MSP=10; base=40;  }
    else if (cidx < 500) { wrel=wr2; wroot=wq2; COUT=10; CIN=15; MSP=8;  base=340; }
    else if (cidx < 550) { wrel=wr3; wroot=wq3; COUT=5;  CIN=10; MSP=5;  base=500; }
    else                 { wrel=wr4; wroot=wq4; COUT=2;  CIN=5;  MSP=3;  base=550; }
    const int r    = cidx - base;
    const int half = r >= COUT * MSP;
    const int q    = r - half * COUT * MSP;
    const int o    = q / MSP, p = q - o * MSP;
    const float* w = half ? wroot : wrel;
    const int c0 = 2 * p, c1 = 2 * p + 1;
    const float v0 = (c0 < CIN) ? w[o * CIN + c0] : 0.f;
    const float v1 = (c1 < CIN) ? w[o * CIN + c1] : 0.f;
    chk[cidx] = __builtin_bit_cast(unsigned, __floats2half2_rn(v0, v1));
}

// ---------------------------------------------------------------------------
// Conv layer: node-per-thread gather with f32 accumulation (v_fma_mix,
// deterministic), dense via v_dot2_f32_f16 (__builtin_amdgcn_fdot2):
// 2 MACs per instruction, f32 accumulator, half2 weights (s_load-uniform).
// ---------------------------------------------------------------------------
template <int CIN, int COUT, int SIN, int SOUT>
__device__ __forceinline__ void conv_layer_h(
    const unsigned* __restrict__ h_in,   // rows stride SIN (half2 words)
    unsigned* __restrict__ h_out,        // rows stride SOUT
    const unsigned* __restrict__ s_edge, // (f16w<<16)|src, sorted by dst
    const unsigned* __restrict__ row_start,
    const unsigned short* __restrict__ perm,
    const unsigned* __restrict__ wrelh,  // [COUT][MS] half2 pairs
    const unsigned* __restrict__ wrooth, // [COUT][MS]
    const float* __restrict__ brel, int tid)
{
    if (tid >= NPG) return;
    const int node = (int)perm[tid];
    constexpr int MS = (CIN + 1) / 2;

    float aggf[MS * 2];
#pragma unroll
    for (int c = 0; c < MS * 2; ++c) aggf[c] = 0.f;

    const unsigned jb = row_start[node], je = row_start[node + 1];
    for (unsigned j = jb; j < je; ++j) {
        const unsigned e  = s_edge[j];
        const float    wf = __half2float(__ushort_as_half((unsigned short)(e >> 16)));
        const unsigned* row = h_in + (e & 0xFFFFu) * SIN;
        unsigned wv[MS];
        if constexpr (SIN == 1) {
            wv[0] = row[0];
        } else {
            const uint4 q0 = *(const uint4*)row;
            wv[0] = q0.x;
            if constexpr (MS > 1) wv[1] = q0.y;
            if constexpr (MS > 2) wv[2] = q0.z;
            if constexpr (MS > 3) wv[3] = q0.w;
            if constexpr (MS > 4) {
                const uint4 q1 = *(const uint4*)(row + 4);
                wv[4] = q1.x;
                if constexpr (MS > 5) wv[5] = q1.y;
                if constexpr (MS > 6) wv[6] = q1.z;
                if constexpr (MS > 7) wv[7] = q1.w;
            }
            if constexpr (MS > 8) {
                const uint4 q2 = *(const uint4*)(row + 8);
                wv[8] = q2.x;
                if constexpr (MS > 9) wv[9] = q2.y;
            }
        }
#pragma unroll
        for (int p = 0; p < MS; ++p) {
            const __half2 h2 = BC2(wv[p]);
            aggf[2*p]     = fmaf(wf, __low2float(h2),  aggf[2*p]);
            aggf[2*p + 1] = fmaf(wf, __high2float(h2), aggf[2*p + 1]);
        }
    }

    // pack agg to half2 pairs (f32 -> f16 once; error ~ feature f16 noise)
    unsigned aggh[MS];
#pragma unroll
    for (int p = 0; p < MS; ++p)
        aggh[p] = __builtin_bit_cast(unsigned,
            __floats2half2_rn(aggf[2*p], aggf[2*p + 1]));

    // own row kept as raw half2 words (no unpack needed)
    unsigned mw[MS];
    {
        const unsigned* me = h_in + node * SIN;
#pragma unroll
        for (int p = 0; p < MS; ++p) mw[p] = me[p];
    }

    // dense via v_dot2_f32_f16: outv[o] = b + dot(agg,wrel[o]) + dot(h,wroot[o])
    float outv[COUT];
#pragma unroll
    for (int o = 0; o < COUT; ++o) {
        float acc = brel[o];
#pragma unroll
        for (int p = 0; p < MS; ++p) {
            acc = __builtin_amdgcn_fdot2(BCH2(aggh[p]), BCH2(wrelh[o * MS + p]),
                                         acc, false);
            acc = __builtin_amdgcn_fdot2(BCH2(mw[p]),   BCH2(wrooth[o * MS + p]),
                                         acc, false);
        }
        outv[o] = fmaxf(acc, 0.f);
    }

    if constexpr (SOUT == 1) {
        h_out[node] = __builtin_bit_cast(unsigned,
            __floats2half2_rn(outv[0], COUT > 1 ? outv[1] : 0.f));
    } else {
        unsigned ow[SOUT];
#pragma unroll
        for (int p = 0; p < SOUT; ++p) {
            const float lo = (2 * p     < COUT) ? outv[2 * p]     : 0.f;
            const float hi = (2 * p + 1 < COUT) ? outv[2 * p + 1] : 0.f;
            ow[p] = __builtin_bit_cast(unsigned, __floats2half2_rn(lo, hi));
        }
        unsigned* orow = h_out + node * SOUT;
#pragma unroll
        for (int qn = 0; qn < SOUT / 4; ++qn)
            *(uint4*)(orow + 4 * qn) =
                make_uint4(ow[4*qn], ow[4*qn+1], ow[4*qn+2], ow[4*qn+3]);
    }
}

__global__ __launch_bounds__(256) void conv_kernel(
    const float* __restrict__ x,
    const int*   __restrict__ eidx,
    const float* __restrict__ ew,
    const unsigned* __restrict__ chk,
    const float* __restrict__ br0, const float* __restrict__ br1,
    const float* __restrict__ br2, const float* __restrict__ br3,
    const float* __restrict__ br4,
    _Float16* __restrict__ H)            // row-major [NG][396] f16
{
    __shared__ __align__(16) unsigned s_edge[EPG];            // 6336 B
    __shared__ unsigned       cnt[256];
    __shared__ unsigned       cursor[256];
    __shared__ unsigned       row_start[NPG + 1];
    __shared__ unsigned       wsum[4];
    __shared__ unsigned       dhist[64];
    __shared__ unsigned       dcur[64];
    __shared__ unsigned short perm[NPG + 2];
    __shared__ __align__(16) unsigned bufA[NPG * SHW];        // 9504 B
    __shared__ __align__(16) unsigned bufB[NPG * SHW];        // 9504 B

    const int g = blockIdx.x, tid = threadIdx.x;
    const int ebase = g * EPG, nbase = g * NPG;
    const int lane = tid & 63, wid = tid >> 6;

    // --- zero feature buffers (pad halves must be 0) ------------------------
    for (int i = tid; i < NPG * SHW; i += 256) { bufA[i] = 0u; bufB[i] = 0u; }

    // --- load all edges once into registers (396 quads over 256 threads) ----
    const int4*   s4 = (const int4*)(eidx + ebase);
    const int4*   d4 = (const int4*)(eidx + ETOT + ebase);
    const float4* w4 = (const float4*)(ew + ebase);
    const int4   sa = s4[tid];
    const int4   da = d4[tid];
    const float4 wa = w4[tid];
    const bool hasb = tid < (EPG / 4 - 256);   // threads 0..139
    int4 sb = {0,0,0,0}, db = {0,0,0,0}; float4 wb = {0,0,0,0};
    if (hasb) { sb = s4[tid + 256]; db = d4[tid + 256]; wb = w4[tid + 256]; }

    cnt[tid] = 0u;
    __syncthreads();
    atomicAdd(&cnt[da.x - nbase], 1u); atomicAdd(&cnt[da.y - nbase], 1u);
    atomicAdd(&cnt[da.z - nbase], 1u); atomicAdd(&cnt[da.w - nbase], 1u);
    if (hasb) {
        atomicAdd(&cnt[db.x - nbase], 1u); atomicAdd(&cnt[db.y - nbase], 1u);
        atomicAdd(&cnt[db.z - nbase], 1u); atomicAdd(&cnt[db.w - nbase], 1u);
    }
    __syncthreads();

    // --- exclusive scan (wave shfl + cross-wave combine) --------------------
    const unsigned v = cnt[tid];
    unsigned inc = v;
#pragma unroll
    for (int s = 1; s < 64; s <<= 1) {
        const unsigned t = (unsigned)__shfl_up((int)inc, s);
        if (lane >= s) inc += t;
    }
    if (lane == 63) wsum[wid] = inc;
    __syncthreads();
    unsigned pre = 0;
    for (int w = 0; w < wid; ++w) pre += wsum[w];
    const unsigned excl = pre + inc - v;
    if (tid <= NPG) row_start[tid] = excl;   // row_start[198] == EPG
    if (tid < NPG)  cursor[tid]    = excl;
    __syncthreads();

    // --- place edges sorted by dst: pack (f16w<<16)|src ---------------------
    {
        auto place = [&](int s, int d, float w) {
            const int dl = d - nbase;
            const unsigned slot = atomicAdd(&cursor[dl], 1u);
            const __half hw = __float2half_rn(w);
            s_edge[slot] = ((unsigned)__half_as_ushort(hw) << 16)
                         | (unsigned)(s - nbase);
        };
        place(sa.x, da.x, wa.x); place(sa.y, da.y, wa.y);
        place(sa.z, da.z, wa.z); place(sa.w, da.w, wa.w);
        if (hasb) {
            place(sb.x, db.x, wb.x); place(sb.y, db.y, wb.y);
            place(sb.z, db.z, wb.z); place(sb.w, db.w, wb.w);
        }
    }

    // pack x (198 x 2 fp32) into half2 words of bufA (stride 1)
    if (tid < NPG) {
        const float2 xv = ((const float2*)x)[nbase + tid];
        bufA[tid] = __builtin_bit_cast(unsigned, __floats2half2_rn(xv.x, xv.y));
    }

    // --- degree-sorted permutation (counting sort over 64 degree bins) ------
    if (tid < 64) dhist[tid] = 0u;
    __syncthreads();
    unsigned mydeg = 0u;
    if (tid < NPG) {
        mydeg = v; if (mydeg > 63u) mydeg = 63u;
        atomicAdd(&dhist[mydeg], 1u);
    }
    __syncthreads();
    if (tid < 64) {
        const unsigned dv = dhist[tid];
        unsigned sc = dv;
#pragma unroll
        for (int s = 1; s < 64; s <<= 1) {
            const unsigned t = (unsigned)__shfl_up((int)sc, s);
            if (lane >= s) sc += t;
        }
        dcur[tid] = sc - dv;
    }
    __syncthreads();
    if (tid < NPG) {
        const unsigned pos = atomicAdd(&dcur[mydeg], 1u);
        perm[pos] = (unsigned short)tid;
    }
    __syncthreads();

    // --- 5 layers, one barrier each (chk bases: 0,40,340,500,550 pairs) -----
    conv_layer_h<2,  20, 1,   SHW>(bufA, bufB, s_edge, row_start, perm,
                                   chk + 0,   chk + 20,        br0, tid);
    __syncthreads();
    conv_layer_h<20, 15, SHW, SHW>(bufB, bufA, s_edge, row_start, perm,
                                   chk + 40,  chk + 40 + 150,  br1, tid);
    __syncthreads();
    conv_layer_h<15, 10, SHW, SHW>(bufA, bufB, s_edge, row_start, perm,
                                   chk + 340, chk + 340 + 80,  br2, tid);
    __syncthreads();
    conv_layer_h<10, 5,  SHW, SHW>(bufB, bufA, s_edge, row_start, perm,
                                   chk + 500, chk + 500 + 25,  br3, tid);
    __syncthreads();
    conv_layer_h<5,  2,  SHW, 1  >(bufA, bufB, s_edge, row_start, perm,
                                   chk + 550, chk + 550 + 6,   br4, tid);
    __syncthreads();

    // --- row-major f16 store: H[g][396] (word = half2 of ch 0,1 per node) ---
    if (tid < NPG)
        ((unsigned*)H)[g * NPG + tid] = bufB[tid];
}

// ---------------------------------------------------------------------------
// MLP as fused MFMA GEMM chain with hi/lo weight split (validated r11/r14).
// 8 graphs per block (512 blocks = 2 blocks/CU, 16 waves/CU).
// ---------------------------------------------------------------------------
__device__ __forceinline__ void zero_words(void* p, int nwords, int tid)
{
    unsigned* u = (unsigned*)p;
    for (int i = tid; i < nwords; i += 512) u[i] = 0u;
}

template<int KC, int NTT, int NOUT, int SIN, int SOUT>
__device__ __forceinline__ void mfma_layer(
    const _Float16* __restrict__ inb,
    _Float16* __restrict__ outb,
    const _Float16* __restrict__ wthi,
    const _Float16* __restrict__ wtlo,
    const float* __restrict__ bias, int tid)
{
    constexpr int NPAD = NTT * 16;
    const int lane = tid & 63, wid = tid >> 6;
    const int lrow = lane & 15, lgrp = lane >> 4;
    const int nt0 = wid;
    if (nt0 >= NTT) return;
    const bool has2 = (nt0 + 8) < NTT;
    const _Float16* aptr = inb + lrow * SIN + lgrp * 4;

    f32x4 acc0 = {0.f, 0.f, 0.f, 0.f};
    f32x4 acc1 = {0.f, 0.f, 0.f, 0.f};
    const int n0 = nt0 * 16 + lrow;
    const int n1 = (nt0 + 8) * 16 + lrow;
    const int boff0 = n0 * 16 + lgrp * 4;
    const int boff1 = n1 * 16 + lgrp * 4;
#pragma unroll 4
    for (int kc = 0; kc < KC; ++kc) {
        const f16x4 a = *(const f16x4*)(aptr + kc * 16);
        const size_t kb = (size_t)kc * (NPAD * 16);
        acc0 = __builtin_amdgcn_mfma_f32_16x16x16f16(
            a, *(const f16x4*)(wthi + kb + boff0), acc0, 0, 0, 0);
        acc0 = __builtin_amdgcn_mfma_f32_16x16x16f16(
            a, *(const f16x4*)(wtlo + kb + boff0), acc0, 0, 0, 0);
        if (has2) {
            acc1 = __builtin_amdgcn_mfma_f32_16x16x16f16(
                a, *(const f16x4*)(wthi + kb + boff1), acc1, 0, 0, 0);
            acc1 = __builtin_amdgcn_mfma_f32_16x16x16f16(
                a, *(const f16x4*)(wtlo + kb + boff1), acc1, 0, 0, 0);
        }
    }
    if (n0 < NOUT) {
        const float bv = bias[n0];
#pragma unroll
        for (int j = 0; j < 4; ++j)
            outb[(lgrp * 4 + j) * SOUT + n0] = (_Float16)fmaxf(acc0[j] + bv, 0.f);
    }
    if (has2 && n1 < NOUT) {
        const float bv = bias[n1];
#pragma unroll
        for (int j = 0; j < 4; ++j)
            outb[(lgrp * 4 + j) * SOUT + n1] = (_Float16)fmaxf(acc1[j] + bv, 0.f);
    }
}

__global__ __launch_bounds__(512) void mlp_mfma_kernel(
    const _Float16* __restrict__ H,
    const _Float16* __restrict__ wtb,
    const float* __restrict__ lb0, const float* __restrict__ lb1,
    const float* __restrict__ lb2, const float* __restrict__ lb3,
    const float* __restrict__ lw4, const float* __restrict__ lb4,
    float* __restrict__ out)
{
    __shared__ __align__(16) _Float16 bufH[16 * 400];
    __shared__ __align__(16) _Float16 bufX[16 * 224];
    __shared__ __align__(16) _Float16 bufY[16 * 128];

    const int tid   = threadIdx.x;
    const int gbase = blockIdx.x * 8;          // 8 graphs per block
    const _Float16* lo = wtb + WTB_SZ;

    {
        const unsigned* Hw = (const unsigned*)H + (size_t)gbase * 198;
        unsigned* bH = (unsigned*)bufH;
        for (int t = tid; t < 16 * 200; t += 512) {
            const int gg = t / 200, w = t - gg * 200;
            bH[gg * 200 + w] = (gg < 8 && w < 198) ? Hw[gg * 198 + w] : 0u;
        }
        zero_words(bufX, 16 * 224 / 2, tid);
        zero_words(bufY, 16 * 128 / 2, tid);
    }
    __syncthreads();

    mfma_layer<25, 13, 200, 400, 224>(bufH, bufX, wtb, lo, lb0, tid);
    __syncthreads();

    zero_words(bufH, 512, tid);
    mfma_layer<13, 7, 100, 224, 128>(bufX, bufY, wtb + WTB1_OFF, lo + WTB1_OFF, lb1, tid);
    __syncthreads();

    zero_words(bufX, 128, tid);
    mfma_layer<7, 4, 50, 128, 64>(bufY, bufH, wtb + WTB2_OFF, lo + WTB2_OFF, lb2, tid);
    __syncthreads();

    mfma_layer<4, 1, 10, 64, 16>(bufH, bufX, wtb + WTB3_OFF, lo + WTB3_OFF, lb3, tid);
    __syncthreads();

    if (tid < 8) {
        float l0 = lb4[0], l1 = lb4[1];
#pragma unroll
        for (int k = 0; k < 10; ++k) {
            const float hv = (float)bufX[tid * 16 + k];
            l0 = fmaf(hv, lw4[k],      l0);
            l1 = fmaf(hv, lw4[10 + k], l1);
        }
        const float m  = fmaxf(l0, l1);
        const float e0 = __expf(l0 - m), e1 = __expf(l1 - m);
        const float inv = 1.f / (e0 + e1);
        float2 p; p.x = e0 * inv; p.y = e1 * inv;
        ((float2*)out)[gbase + tid] = p;
    }
}

extern "C" void kernel_launch(void* const* d_in, const int* in_sizes, int n_in,
                              void* d_out, int out_size, void* d_ws, size_t ws_size,
                              hipStream_t stream)
{
    const float* x    = (const float*)d_in[0];
    const int*   eidx = (const int*)  d_in[1];
    const float* ew   = (const float*)d_in[2];

    const float* wr[5]; const float* br[5]; const float* wq[5];
    for (int i = 0; i < 5; ++i) {
        wr[i] = (const float*)d_in[3 + 3 * i];
        br[i] = (const float*)d_in[4 + 3 * i];
        wq[i] = (const float*)d_in[5 + 3 * i];
    }
    const float* lw[5]; const float* lb[5];
    for (int i = 0; i < 5; ++i) {
        lw[i] = (const float*)d_in[18 + 2 * i];
        lb[i] = (const float*)d_in[19 + 2 * i];
    }

    _Float16* wsH = (_Float16*)d_ws;                  // H: [NG][396] f16
    _Float16* wtb = wsH + (size_t)H_F16S;             // MLP weights hi+lo
    unsigned* chk = (unsigned*)(wtb + (size_t)(2 * WTB_SZ)); // conv half2 pairs

    const int total_pack = 2 * WTB_SZ + CHK_PAIRS;
    wpack_kernel<<<(total_pack + 255) / 256, 256, 0, stream>>>(
        lw[0], lw[1], lw[2], lw[3],
        wr[0], wq[0], wr[1], wq[1], wr[2], wq[2], wr[3], wq[3], wr[4], wq[4],
        wtb, chk);

    conv_kernel<<<NG, 256, 0, stream>>>(
        x, eidx, ew, chk,
        br[0], br[1], br[2], br[3], br[4],
        wsH);

    mlp_mfma_kernel<<<NG / 8, 512, 0, stream>>>(
        wsH, wtb,
        lb[0], lb[1], lb[2], lb[3],
        lw[4], lb[4],
        (float*)d_out);
}